// Round 9
// baseline (678.388 us; speedup 1.0000x reference)
//
#include <hip/hip_runtime.h>
#include <hip/hip_bf16.h>
#include <stdint.h>

// ---------------- problem constants ----------------
#define N_TOK 8192
#define DIM   1024
#define FF    4096
#define NEXP  8
#define MAXT  136    // 128-row tiles: sum ceil(ce/128) <= 128+8; 136 = 8 XCDs * 17
#define WN4   (NEXP * FF * DIM / 4)   // float4 count of one weight tensor

// ---------------- workspace layout (bytes) ----------------
#define OFF_COUNTS 0ull
#define OFF_NT     64ull
#define OFF_T128   8192ull            // 136*16
#define OFF_IDX    16384ull           // 8*8192*4
#define OFF_GATE   278528ull
#define OFF_XB     1048576ull         // 8192*1024*2
#define OFF_H      17825792ull        // 17408*4096*2 fits in 150,994,944
#define OFF_WB     168820736ull       // 8*4096*1024*2 = 67,108,864 (w1b; w2b aliased if small ws)
#define OFF_W2B    235929600ull       // separate w2b when workspace permits
#define NEED       235929600ull
#define NEED2      303038464ull       // OFF_W2B + 67,108,864

typedef __attribute__((ext_vector_type(8))) short s16x8;   // 8 bf16 MFMA frag
typedef __attribute__((ext_vector_type(4))) float f32x4;   // MFMA accum

__device__ __forceinline__ unsigned short f2bf(float f) {
  union { float f; unsigned int u; } v; v.f = f;
  unsigned int u = v.u;
  unsigned int r = (u + 0x7FFFu + ((u >> 16) & 1u)) >> 16;  // RNE
  return (unsigned short)r;
}

// gelu: 0.5*x*(1+erf(x/sqrt2)), erf via A&S 7.1.26 (|err|<1.5e-7)
__device__ __forceinline__ float gelu_f(float x) {
  float s = x * 0.70710678118654752f;
  float a = fabsf(s);
  float t = 1.0f / fmaf(0.3275911f, a, 1.0f);
  float p = t * fmaf(t, fmaf(t, fmaf(t, fmaf(t, 1.061405429f, -1.453152027f),
                                     1.421413741f), -0.284496736f), 0.254829592f);
  float e = __expf(-a * a);
  float erf_a = 1.0f - p * e;
  float erf_s = (s >= 0.0f) ? erf_a : -erf_a;
  return 0.5f * x * (1.0f + erf_s);
}

// async global -> LDS, 16B per lane (dest = wave-uniform base + lane*16)
__device__ __forceinline__ void load_lds16(const void* g, void* l) {
  __builtin_amdgcn_global_load_lds(
      (const __attribute__((address_space(1))) unsigned int*)g,
      (__attribute__((address_space(3))) unsigned int*)l, 16, 0, 0);
}

// ---------------- f32 -> bf16 bulk convert (fallback path) ----------------
__global__ __launch_bounds__(256) void cvt_f32_bf16(const float4* __restrict__ in,
                                                    ushort4* __restrict__ out, int n4) {
  int i = blockIdx.x * 256 + threadIdx.x;
  int stride = gridDim.x * 256;
  for (; i < n4; i += stride) {
    float4 f = in[i];
    ushort4 u;
    u.x = f2bf(f.x); u.y = f2bf(f.y); u.z = f2bf(f.z); u.w = f2bf(f.w);
    out[i] = u;
  }
}

// ---------------- router (even blocks) + w1 cvt (odd blocks) ----------------
// Router: 1 wave/token, fp32 logits, exact top-2, atomic expert lists; also
// emits xb (bf16 x). Fused w1 cvt streams under/behind the router's short run.
__global__ __launch_bounds__(256) void router_cvt(
    const float* __restrict__ x, const float* __restrict__ rw,
    int* __restrict__ counts, int* __restrict__ idx_list, float* __restrict__ gate_list,
    unsigned short* __restrict__ xb,
    const float4* __restrict__ w1f, ushort4* __restrict__ w1o) {
  if (blockIdx.x & 1) {  // ---- w1 conversion blocks (2048 of them)
    int i = (blockIdx.x >> 1) * 256 + threadIdx.x;
    for (; i < WN4; i += 2048 * 256) {
      float4 f = w1f[i];
      ushort4 u;
      u.x = f2bf(f.x); u.y = f2bf(f.y); u.z = f2bf(f.z); u.w = f2bf(f.w);
      w1o[i] = u;
    }
    return;
  }
  int wid = threadIdx.x >> 6;
  int lane = threadIdx.x & 63;
  int token = (blockIdx.x >> 1) * 4 + wid;

  const float4* xr = (const float4*)(x + (size_t)token * DIM);
  ushort4* xw = (ushort4*)(xb + (size_t)token * DIM);
  float p[NEXP];
#pragma unroll
  for (int e = 0; e < NEXP; ++e) p[e] = 0.f;
#pragma unroll
  for (int c = 0; c < 4; ++c) {
    float4 xv = xr[c * 64 + lane];
    ushort4 u;
    u.x = f2bf(xv.x); u.y = f2bf(xv.y); u.z = f2bf(xv.z); u.w = f2bf(xv.w);
    xw[c * 64 + lane] = u;
#pragma unroll
    for (int e = 0; e < NEXP; ++e) {
      float4 wv = ((const float4*)(rw + (size_t)e * DIM))[c * 64 + lane];
      p[e] += xv.x * wv.x + xv.y * wv.y + xv.z * wv.z + xv.w * wv.w;
    }
  }
#pragma unroll
  for (int e = 0; e < NEXP; ++e) {
    float v = p[e];
#pragma unroll
    for (int off = 32; off > 0; off >>= 1) v += __shfl_xor(v, off, 64);
    p[e] = v;
  }
  if (lane == 0) {
    int e0 = 0; float v0 = p[0];
#pragma unroll
    for (int e = 1; e < NEXP; ++e) if (p[e] > v0) { v0 = p[e]; e0 = e; }
    int e1 = (e0 == 0) ? 1 : 0; float v1 = -3.4e38f;
#pragma unroll
    for (int e = 0; e < NEXP; ++e) if (e != e0 && p[e] > v1) { v1 = p[e]; e1 = e; }
    float ex = __expf(v1 - v0);
    float g0 = 1.0f / (1.0f + ex);
    float g1 = ex / (1.0f + ex);
    int p0 = atomicAdd(&counts[e0], 1);
    idx_list[e0 * N_TOK + p0] = token;
    gate_list[e0 * N_TOK + p0] = g0;
    int p1 = atomicAdd(&counts[e1], 1);
    idx_list[e1 * N_TOK + p1] = token;
    gate_list[e1 * N_TOK + p1] = g1;
  }
}

// ---------------- schedule: counts -> 128-row tile table (1 wave) ------------
__global__ void schedule_kernel(const int* __restrict__ counts, int4* __restrict__ t128,
                                int* __restrict__ nt) {
  int lane = threadIdx.x;
  int base[NEXP + 1], gb[NEXP];
  int b = 0, g = 0;
#pragma unroll
  for (int e = 0; e < NEXP; ++e) {
    base[e] = b; gb[e] = g;
    int n2 = (counts[e] + 127) >> 7;
    b += n2; g += n2 << 7;
  }
  base[NEXP] = b;
  if (lane == 0) nt[0] = b;
  for (int i = lane; i < b; i += 64) {
    int e = 0;
#pragma unroll
    for (int q = 0; q < NEXP - 1; ++q) if (i >= base[q + 1]) e = q + 1;
    int k = i - base[e];
    t128[i] = make_int4(e, k << 7, gb[e] + (k << 7), 0);
  }
}

// ---------------- grouped GEMM: 128x128, BK=64, 4 waves, single buffer -------
// Proven r8 skeleton: {stage; sync; ds_read+MFMA; sync} per K-tile; latency
// hidden by co-resident blocks (m114). L2-aware chunked XCD mapping (r8).
// LDS conflict-free via source-pre-swizzled 16B-slot XOR (r3: 0 conflicts).
// FUSE (GEMM1 only): grid doubled; 16-block groups = 8 GEMM + 8 cvt blocks.
// sub<8 -> GEMM block o = g*8+sub (preserves o&7 XCD + chunk order exactly);
// sub>=8 -> short w2 f32->bf16 streaming block (~31 KB each) that drafts on
// GEMM1's idle HBM bandwidth (GEMM1 runs at ~15% of peak). w2b is complete
// when this kernel finishes -> GEMM2 (stream-ordered) sees converted weights.
// EPI==1: H[gbase+r] = gelu(A_gathered @ W^T) (bf16).
// EPI==2: atomicAdd(Out[token], gate * (H @ W^T)).
template <int KDIM, int EPI, int TPX, int CW, bool FUSE>
__global__ __launch_bounds__(256, 4) void moe_g(
    const unsigned short* __restrict__ Abase, const unsigned short* __restrict__ Bb,
    unsigned short* __restrict__ Hout, float* __restrict__ Out,
    const int* __restrict__ idx_list, const float* __restrict__ gate_list,
    const int* __restrict__ counts, const int4* __restrict__ table,
    const int* __restrict__ n_tiles,
    const float4* __restrict__ cvt_src, ushort4* __restrict__ cvt_dst) {
  int o;
  if constexpr (FUSE) {
    const int g = blockIdx.x >> 4, sub = blockIdx.x & 15;
    if (sub >= 8) {  // ---- w2 conversion blocks (half the grid, short)
      const int c = g * 8 + (sub - 8);            // 0 .. ngemm-1
      const int ncvt = (int)(gridDim.x >> 1);
      for (int i = c * 256 + threadIdx.x; i < WN4; i += ncvt * 256) {
        float4 f = cvt_src[i];
        ushort4 u;
        u.x = f2bf(f.x); u.y = f2bf(f.y); u.z = f2bf(f.z); u.w = f2bf(f.w);
        cvt_dst[i] = u;
      }
      return;
    }
    o = g * 8 + sub;
  } else {
    o = blockIdx.x;
  }
  const int xcd = o & 7, r0 = o >> 3;
  const int chunk = r0 / (TPX * CW), q = r0 % (TPX * CW);
  const int ty = xcd * TPX + q / CW;
  const int cx = chunk * CW + q % CW;
  if (ty >= *n_tiles) return;
  int4 te = table[ty];
  const int e = te.x, row_start = te.y, gbase = te.z;
  const int ce = counts[e];
  const int tid = threadIdx.x;
  const int wid = tid >> 6, lane = tid & 63;
  const int colT = cx * 128;

  __shared__ unsigned short Al[128 * 64];
  __shared__ unsigned short Bl[128 * 64];

  // staging: thread -> rows {i*32+sr}, phys 16B-slot tid&7; source pre-swizzled
  const int sr = tid >> 3;
  const int scol = ((tid & 7) ^ (sr & 7)) * 8;
  size_t aoff[4], boff[4];
#pragma unroll
  for (int i = 0; i < 4; ++i) {
    int r = i * 32 + sr;
    if constexpr (EPI == 1) {
      int rl = row_start + r; if (rl >= ce) rl = ce - 1;   // clamp padded rows
      int tok = idx_list[e * N_TOK + rl];
      aoff[i] = ((size_t)tok * KDIM + scol) * 2;
    } else {
      aoff[i] = ((size_t)(gbase + r) * KDIM + scol) * 2;
    }
    boff[i] = ((size_t)e * FF * DIM + (size_t)(colT + r) * KDIM + scol) * 2;
  }
  const char* Ag = (const char*)Abase;
  const char* Bg = (const char*)Bb;
  const int NT = KDIM / 64;

  const int wr = (wid >> 1) * 64, wc = (wid & 1) * 64;   // wave 64x64 sub-tile
  const int r16 = lane & 15, kg = lane >> 4;
  const int x7 = r16 & 7;

  f32x4 acc[4][4] = {};

  for (int t = 0; t < NT; ++t) {
    {
      char* da = (char*)Al + tid * 16;
      char* db = (char*)Bl + tid * 16;
      size_t ko = (size_t)t * 128;   // 64 elems * 2B
#pragma unroll
      for (int i = 0; i < 4; ++i) load_lds16(Ag + aoff[i] + ko, da + i * 4096);
#pragma unroll
      for (int i = 0; i < 4; ++i) load_lds16(Bg + boff[i] + ko, db + i * 4096);
    }
    __syncthreads();
    const char* Ap = (const char*)Al + (wr + r16) * 128;
    const char* Bp = (const char*)Bl + (wc + r16) * 128;
#pragma unroll
    for (int kf = 0; kf < 2; ++kf) {
      const int so = ((kf * 4 + kg) ^ x7) * 16;   // swizzled 16B-slot
      s16x8 a[4], b[4];
#pragma unroll
      for (int m = 0; m < 4; ++m) a[m] = *(const s16x8*)(Ap + m * 2048 + so);
#pragma unroll
      for (int n = 0; n < 4; ++n) b[n] = *(const s16x8*)(Bp + n * 2048 + so);
#pragma unroll
      for (int m = 0; m < 4; ++m)
#pragma unroll
        for (int n = 0; n < 4; ++n)
          acc[m][n] = __builtin_amdgcn_mfma_f32_16x16x32_bf16(a[m], b[n], acc[m][n], 0, 0, 0);
    }
    __syncthreads();
  }

  if constexpr (EPI == 1) {
#pragma unroll
    for (int m = 0; m < 4; ++m) {
      const int row_l = wr + m * 16 + kg * 4;
#pragma unroll
      for (int j = 0; j < 4; ++j) {
        size_t hrow = (size_t)(gbase + row_l + j) * FF + colT + wc;
#pragma unroll
        for (int n = 0; n < 4; ++n)
          Hout[hrow + n * 16 + r16] = f2bf(gelu_f(acc[m][n][j]));
      }
    }
  } else {
#pragma unroll
    for (int m = 0; m < 4; ++m) {
      const int row_l = wr + m * 16 + kg * 4;
#pragma unroll
      for (int j = 0; j < 4; ++j) {
        int r = row_start + row_l + j;
        if (r < ce) {
          int tok = idx_list[e * N_TOK + r];
          float g = gate_list[e * N_TOK + r];
          float* orow = Out + (size_t)tok * DIM + colT + wc;
#pragma unroll
          for (int n = 0; n < 4; ++n)
            atomicAdd(&orow[n * 16 + r16], acc[m][n][j] * g);
        }
      }
    }
  }
}

// ---------------- launch ----------------
extern "C" void kernel_launch(void* const* d_in, const int* in_sizes, int n_in,
                              void* d_out, int out_size, void* d_ws, size_t ws_size,
                              hipStream_t stream) {
  const float* x  = (const float*)d_in[0];
  const float* rw = (const float*)d_in[1];
  const float* w1 = (const float*)d_in[2];
  const float* w2 = (const float*)d_in[3];
  float* out = (float*)d_out;
  char* ws = (char*)d_ws;
  if (ws_size < NEED) return;
  const bool sep = ws_size >= NEED2;   // ws_size is fixed -> deterministic

  int*   counts    = (int*)(ws + OFF_COUNTS);
  int*   nt        = (int*)(ws + OFF_NT);
  int4*  t128      = (int4*)(ws + OFF_T128);
  int*   idx_list  = (int*)(ws + OFF_IDX);
  float* gate_list = (float*)(ws + OFF_GATE);
  unsigned short* xb  = (unsigned short*)(ws + OFF_XB);
  unsigned short* h   = (unsigned short*)(ws + OFF_H);
  unsigned short* wb  = (unsigned short*)(ws + OFF_WB);
  unsigned short* w2b = (unsigned short*)(ws + OFF_W2B);

  hipMemsetAsync(d_out, 0, (size_t)N_TOK * DIM * sizeof(float), stream);
  hipMemsetAsync(ws, 0, 256, stream);  // counts + nt

  // router (even blocks) + w1->bf16 (odd blocks); both complete before GEMM1
  router_cvt<<<4096, 256, 0, stream>>>(x, rw, counts, idx_list, gate_list, xb,
                                       (const float4*)w1, (ushort4*)wb);
  schedule_kernel<<<1, 64, 0, stream>>>(counts, t128, nt);

  if (sep) {
    // GEMM1 (4352 blocks) + fused w2->bf16 (4352 short blocks), 16-interleaved
    moe_g<DIM, 1, 17, 8, true><<<2 * 32 * MAXT, 256, 0, stream>>>(
        xb, wb, h, nullptr, idx_list, gate_list, counts, t128, nt,
        (const float4*)w2, (ushort4*)w2b);
    moe_g<FF, 2, 17, 4, false><<<8 * MAXT, 256, 0, stream>>>(
        h, w2b, nullptr, out, idx_list, gate_list, counts, t128, nt, nullptr, nullptr);
  } else {
    moe_g<DIM, 1, 17, 8, false><<<32 * MAXT, 256, 0, stream>>>(
        xb, wb, h, nullptr, idx_list, gate_list, counts, t128, nt, nullptr, nullptr);
    cvt_f32_bf16<<<2048, 256, 0, stream>>>((const float4*)w2, (ushort4*)wb, WN4);
    moe_g<FF, 2, 17, 4, false><<<8 * MAXT, 256, 0, stream>>>(
        h, wb, nullptr, out, idx_list, gate_list, counts, t128, nt, nullptr, nullptr);
  }
}

// Round 10
// 646.112 us; speedup vs baseline: 1.0500x; 1.0500x over previous
//
#include <hip/hip_runtime.h>
#include <hip/hip_bf16.h>
#include <stdint.h>

// ---------------- problem constants ----------------
#define N_TOK 8192
#define DIM   1024
#define FF    4096
#define NEXP  8
#define MAXT  136    // 128-row tiles: sum ceil(ce/128) <= 135; 136 = 8 XCDs * 17
#define WN4   (NEXP * FF * DIM / 4)   // float4 count of one weight tensor (8388608)

// ---------------- workspace layout (bytes) ----------------
#define OFF_COUNTS 0ull
#define OFF_NT     64ull
#define OFF_T128   8192ull            // 136*16
#define OFF_IDX    16384ull           // 8*8192*4
#define OFF_GATE   278528ull
#define OFF_XB     1048576ull         // 8192*1024*2
#define OFF_H      17825792ull        // 17408*4096*2 fits in 150,994,944
#define OFF_WB     168820736ull       // 8*4096*1024*2 (w1b; w2b aliased if small ws)
#define OFF_W2B    235929600ull       // separate w2b when workspace permits
#define NEED       235929600ull
#define NEED2      303038464ull       // OFF_W2B + 67,108,864

typedef __attribute__((ext_vector_type(8))) short s16x8;   // 8 bf16 MFMA frag
typedef __attribute__((ext_vector_type(4))) float f32x4;   // MFMA accum

__device__ __forceinline__ unsigned short f2bf(float f) {
  union { float f; unsigned int u; } v; v.f = f;
  unsigned int u = v.u;
  unsigned int r = (u + 0x7FFFu + ((u >> 16) & 1u)) >> 16;  // RNE
  return (unsigned short)r;
}
__device__ __forceinline__ ushort4 bf4(float4 f) {
  ushort4 u;
  u.x = f2bf(f.x); u.y = f2bf(f.y); u.z = f2bf(f.z); u.w = f2bf(f.w);
  return u;
}

// gelu: 0.5*x*(1+erf(x/sqrt2)), erf via A&S 7.1.26 (|err|<1.5e-7)
__device__ __forceinline__ float gelu_f(float x) {
  float s = x * 0.70710678118654752f;
  float a = fabsf(s);
  float t = 1.0f / fmaf(0.3275911f, a, 1.0f);
  float p = t * fmaf(t, fmaf(t, fmaf(t, fmaf(t, 1.061405429f, -1.453152027f),
                                     1.421413741f), -0.284496736f), 0.254829592f);
  float e = __expf(-a * a);
  float erf_a = 1.0f - p * e;
  float erf_s = (s >= 0.0f) ? erf_a : -erf_a;
  return 0.5f * x * (1.0f + erf_s);
}

// async global -> LDS, 16B per lane (dest = wave-uniform base + lane*16)
__device__ __forceinline__ void load_lds16(const void* g, void* l) {
  __builtin_amdgcn_global_load_lds(
      (const __attribute__((address_space(1))) unsigned int*)g,
      (__attribute__((address_space(3))) unsigned int*)l, 16, 0, 0);
}

// ---------------- f32 -> bf16 bulk convert (serial fallback) ----------------
__global__ __launch_bounds__(256) void cvt_f32_bf16(const float4* __restrict__ in,
                                                    ushort4* __restrict__ out, int n4) {
  int i = blockIdx.x * 256 + threadIdx.x;
  int stride = gridDim.x * 256;
  for (; i < n4; i += stride) out[i] = bf4(in[i]);
}

// ---------------- router (8/9 of blocks) + fat w1-cvt blocks (1/9) ----------
// grid = 2304: bid%9==8 -> one of 256 cvt blocks (4-deep ILP streaming);
// else token block tb = bid - (bid+1)/9 (0..2047), 4 tokens per block.
__global__ __launch_bounds__(256) void router_cvt(
    const float* __restrict__ x, const float* __restrict__ rw,
    int* __restrict__ counts, int* __restrict__ idx_list, float* __restrict__ gate_list,
    unsigned short* __restrict__ xb,
    const float4* __restrict__ w1f, ushort4* __restrict__ w1o) {
  const int bid = blockIdx.x;
  if ((bid + 1) % 9 == 0) {  // ---- 256 fat w1-cvt blocks
    const int c = (bid + 1) / 9 - 1;
    const int STR = 256 * 256;
    int i = c * 256 + (int)threadIdx.x;
    for (; i + 3 * STR < WN4; i += 4 * STR) {
      float4 f0 = w1f[i], f1 = w1f[i + STR], f2 = w1f[i + 2 * STR], f3 = w1f[i + 3 * STR];
      w1o[i] = bf4(f0); w1o[i + STR] = bf4(f1);
      w1o[i + 2 * STR] = bf4(f2); w1o[i + 3 * STR] = bf4(f3);
    }
    for (; i < WN4; i += STR) w1o[i] = bf4(w1f[i]);
    return;
  }
  const int tb = bid - (bid + 1) / 9;
  int wid = threadIdx.x >> 6;
  int lane = threadIdx.x & 63;
  int token = tb * 4 + wid;

  const float4* xr = (const float4*)(x + (size_t)token * DIM);
  ushort4* xw = (ushort4*)(xb + (size_t)token * DIM);
  float p[NEXP];
#pragma unroll
  for (int e = 0; e < NEXP; ++e) p[e] = 0.f;
#pragma unroll
  for (int c = 0; c < 4; ++c) {
    float4 xv = xr[c * 64 + lane];
    xw[c * 64 + lane] = bf4(xv);
#pragma unroll
    for (int e = 0; e < NEXP; ++e) {
      float4 wv = ((const float4*)(rw + (size_t)e * DIM))[c * 64 + lane];
      p[e] += xv.x * wv.x + xv.y * wv.y + xv.z * wv.z + xv.w * wv.w;
    }
  }
#pragma unroll
  for (int e = 0; e < NEXP; ++e) {
    float v = p[e];
#pragma unroll
    for (int off = 32; off > 0; off >>= 1) v += __shfl_xor(v, off, 64);
    p[e] = v;
  }
  if (lane == 0) {
    int e0 = 0; float v0 = p[0];
#pragma unroll
    for (int e = 1; e < NEXP; ++e) if (p[e] > v0) { v0 = p[e]; e0 = e; }
    int e1 = (e0 == 0) ? 1 : 0; float v1 = -3.4e38f;
#pragma unroll
    for (int e = 0; e < NEXP; ++e) if (e != e0 && p[e] > v1) { v1 = p[e]; e1 = e; }
    float ex = __expf(v1 - v0);
    float g0 = 1.0f / (1.0f + ex);
    float g1 = ex / (1.0f + ex);
    int p0 = atomicAdd(&counts[e0], 1);
    idx_list[e0 * N_TOK + p0] = token;
    gate_list[e0 * N_TOK + p0] = g0;
    int p1 = atomicAdd(&counts[e1], 1);
    idx_list[e1 * N_TOK + p1] = token;
    gate_list[e1 * N_TOK + p1] = g1;
  }
}

// ---------------- schedule: counts -> 128-row tile table (1 wave) ------------
__global__ void schedule_kernel(const int* __restrict__ counts, int4* __restrict__ t128,
                                int* __restrict__ nt) {
  int lane = threadIdx.x;
  int base[NEXP + 1], gb[NEXP];
  int b = 0, g = 0;
#pragma unroll
  for (int e = 0; e < NEXP; ++e) {
    base[e] = b; gb[e] = g;
    int n2 = (counts[e] + 127) >> 7;
    b += n2; g += n2 << 7;
  }
  base[NEXP] = b;
  if (lane == 0) nt[0] = b;
  for (int i = lane; i < b; i += 64) {
    int e = 0;
#pragma unroll
    for (int q = 0; q < NEXP - 1; ++q) if (i >= base[q + 1]) e = q + 1;
    int k = i - base[e];
    t128[i] = make_int4(e, k << 7, gb[e] + (k << 7), 0);
  }
}

// ---------------- grouped GEMM: 128x128, BK=64, 4 waves, single buffer -------
// Proven r8 skeleton: {stage; sync; ds_read+MFMA; sync} per K-tile; latency
// hidden by co-resident blocks (m114). L2-aware chunked XCD mapping (r8):
// xcd = bid&7 (matches hw round-robin), r0 = per-XCD slot; chunk/ty/cx walk.
// LDS conflict-free via source-pre-swizzled 16B-slot XOR (r3: 0 conflicts).
// FUSE (GEMM1, sep-ws only): per-XCD r has 578 slots = 544 GEMM + 34 cvt; the
// cvt slots sit at every 17th position ((r+1)%17==0) -> at most ~6% of resident
// blocks are cvt at any time (r9's 1:1 interleave cost −78 us; this keeps the
// m114 co-residency for GEMM while w2 f32->bf16 drafts on GEMM1's idle HBM
// bandwidth, ~1.8 TB/s of the ~5 TB/s headroom). Fat cvt blocks, 4-deep ILP.
// EPI==1: H[gbase+r] = gelu(A_gathered @ W^T) (bf16).
// EPI==2: atomicAdd(Out[token], gate * (H @ W^T)).
template <int KDIM, int EPI, int TPX, int CW, bool FUSE>
__global__ __launch_bounds__(256, 4) void moe_g(
    const unsigned short* __restrict__ Abase, const unsigned short* __restrict__ Bb,
    unsigned short* __restrict__ Hout, float* __restrict__ Out,
    const int* __restrict__ idx_list, const float* __restrict__ gate_list,
    const int* __restrict__ counts, const int4* __restrict__ table,
    const int* __restrict__ n_tiles,
    const float4* __restrict__ cvt_src, ushort4* __restrict__ cvt_dst) {
  int xcd, r0;
  if constexpr (FUSE) {
    const int bid = blockIdx.x;           // grid = 8 * 578
    xcd = bid & 7;
    const int r = bid >> 3;               // 0..577 per XCD
    if ((r + 1) % 17 == 0) {              // ---- 34 cvt slots per XCD (272 total)
      const int c = xcd * 34 + (r + 1) / 17 - 1;
      const int STR = 272 * 256;
      int i = c * 256 + (int)threadIdx.x;
      for (; i + 3 * STR < WN4; i += 4 * STR) {
        float4 f0 = cvt_src[i], f1 = cvt_src[i + STR];
        float4 f2 = cvt_src[i + 2 * STR], f3 = cvt_src[i + 3 * STR];
        cvt_dst[i] = bf4(f0); cvt_dst[i + STR] = bf4(f1);
        cvt_dst[i + 2 * STR] = bf4(f2); cvt_dst[i + 3 * STR] = bf4(f3);
      }
      for (; i < WN4; i += STR) cvt_dst[i] = bf4(cvt_src[i]);
      return;
    }
    r0 = r - (r + 1) / 17;                // 0..543: identical walk to non-fused
  } else {
    xcd = blockIdx.x & 7;
    r0 = blockIdx.x >> 3;
  }
  const int chunk = r0 / (TPX * CW), q = r0 % (TPX * CW);
  const int ty = xcd * TPX + q / CW;
  const int cx = chunk * CW + q % CW;
  if (ty >= *n_tiles) return;
  int4 te = table[ty];
  const int e = te.x, row_start = te.y, gbase = te.z;
  const int ce = counts[e];
  const int tid = threadIdx.x;
  const int wid = tid >> 6, lane = tid & 63;
  const int colT = cx * 128;

  __shared__ unsigned short Al[128 * 64];
  __shared__ unsigned short Bl[128 * 64];

  // staging: thread -> rows {i*32+sr}, phys 16B-slot tid&7; source pre-swizzled
  const int sr = tid >> 3;
  const int scol = ((tid & 7) ^ (sr & 7)) * 8;
  size_t aoff[4], boff[4];
#pragma unroll
  for (int i = 0; i < 4; ++i) {
    int r = i * 32 + sr;
    if constexpr (EPI == 1) {
      int rl = row_start + r; if (rl >= ce) rl = ce - 1;   // clamp padded rows
      int tok = idx_list[e * N_TOK + rl];
      aoff[i] = ((size_t)tok * KDIM + scol) * 2;
    } else {
      aoff[i] = ((size_t)(gbase + r) * KDIM + scol) * 2;
    }
    boff[i] = ((size_t)e * FF * DIM + (size_t)(colT + r) * KDIM + scol) * 2;
  }
  const char* Ag = (const char*)Abase;
  const char* Bg = (const char*)Bb;
  const int NT = KDIM / 64;

  const int wr = (wid >> 1) * 64, wc = (wid & 1) * 64;   // wave 64x64 sub-tile
  const int r16 = lane & 15, kg = lane >> 4;
  const int x7 = r16 & 7;

  f32x4 acc[4][4] = {};

  for (int t = 0; t < NT; ++t) {
    {
      char* da = (char*)Al + tid * 16;
      char* db = (char*)Bl + tid * 16;
      size_t ko = (size_t)t * 128;   // 64 elems * 2B
#pragma unroll
      for (int i = 0; i < 4; ++i) load_lds16(Ag + aoff[i] + ko, da + i * 4096);
#pragma unroll
      for (int i = 0; i < 4; ++i) load_lds16(Bg + boff[i] + ko, db + i * 4096);
    }
    __syncthreads();
    const char* Ap = (const char*)Al + (wr + r16) * 128;
    const char* Bp = (const char*)Bl + (wc + r16) * 128;
#pragma unroll
    for (int kf = 0; kf < 2; ++kf) {
      const int so = ((kf * 4 + kg) ^ x7) * 16;   // swizzled 16B-slot
      s16x8 a[4], b[4];
#pragma unroll
      for (int m = 0; m < 4; ++m) a[m] = *(const s16x8*)(Ap + m * 2048 + so);
#pragma unroll
      for (int n = 0; n < 4; ++n) b[n] = *(const s16x8*)(Bp + n * 2048 + so);
#pragma unroll
      for (int m = 0; m < 4; ++m)
#pragma unroll
        for (int n = 0; n < 4; ++n)
          acc[m][n] = __builtin_amdgcn_mfma_f32_16x16x32_bf16(a[m], b[n], acc[m][n], 0, 0, 0);
    }
    __syncthreads();
  }

  if constexpr (EPI == 1) {
#pragma unroll
    for (int m = 0; m < 4; ++m) {
      const int row_l = wr + m * 16 + kg * 4;
#pragma unroll
      for (int j = 0; j < 4; ++j) {
        size_t hrow = (size_t)(gbase + row_l + j) * FF + colT + wc;
#pragma unroll
        for (int n = 0; n < 4; ++n)
          Hout[hrow + n * 16 + r16] = f2bf(gelu_f(acc[m][n][j]));
      }
    }
  } else {
#pragma unroll
    for (int m = 0; m < 4; ++m) {
      const int row_l = wr + m * 16 + kg * 4;
#pragma unroll
      for (int j = 0; j < 4; ++j) {
        int r = row_start + row_l + j;
        if (r < ce) {
          int tok = idx_list[e * N_TOK + r];
          float g = gate_list[e * N_TOK + r];
          float* orow = Out + (size_t)tok * DIM + colT + wc;
#pragma unroll
          for (int n = 0; n < 4; ++n)
            atomicAdd(&orow[n * 16 + r16], acc[m][n][j] * g);
        }
      }
    }
  }
}

// ---------------- launch ----------------
extern "C" void kernel_launch(void* const* d_in, const int* in_sizes, int n_in,
                              void* d_out, int out_size, void* d_ws, size_t ws_size,
                              hipStream_t stream) {
  const float* x  = (const float*)d_in[0];
  const float* rw = (const float*)d_in[1];
  const float* w1 = (const float*)d_in[2];
  const float* w2 = (const float*)d_in[3];
  float* out = (float*)d_out;
  char* ws = (char*)d_ws;
  if (ws_size < NEED) return;
  const bool sep = ws_size >= NEED2;   // ws_size is fixed -> deterministic

  int*   counts    = (int*)(ws + OFF_COUNTS);
  int*   nt        = (int*)(ws + OFF_NT);
  int4*  t128      = (int4*)(ws + OFF_T128);
  int*   idx_list  = (int*)(ws + OFF_IDX);
  float* gate_list = (float*)(ws + OFF_GATE);
  unsigned short* xb  = (unsigned short*)(ws + OFF_XB);
  unsigned short* h   = (unsigned short*)(ws + OFF_H);
  unsigned short* wb  = (unsigned short*)(ws + OFF_WB);
  unsigned short* w2b = (unsigned short*)(ws + OFF_W2B);

  hipMemsetAsync(d_out, 0, (size_t)N_TOK * DIM * sizeof(float), stream);
  hipMemsetAsync(ws, 0, 256, stream);  // counts + nt

  // router (2048 blocks) + fat w1->bf16 blocks (256), 8:1 interleave
  router_cvt<<<2304, 256, 0, stream>>>(x, rw, counts, idx_list, gate_list, xb,
                                       (const float4*)w1, (ushort4*)wb);
  schedule_kernel<<<1, 64, 0, stream>>>(counts, t128, nt);

  if (sep) {
    // GEMM1 (544 GEMM + 34 cvt slots per XCD) * 8 = 4624 blocks, 16:1 interleave
    moe_g<DIM, 1, 17, 8, true><<<8 * 578, 256, 0, stream>>>(
        xb, wb, h, nullptr, idx_list, gate_list, counts, t128, nt,
        (const float4*)w2, (ushort4*)w2b);
    moe_g<FF, 2, 17, 4, false><<<8 * MAXT, 256, 0, stream>>>(
        h, w2b, nullptr, out, idx_list, gate_list, counts, t128, nt, nullptr, nullptr);
  } else {
    moe_g<DIM, 1, 17, 8, false><<<32 * MAXT, 256, 0, stream>>>(
        xb, wb, h, nullptr, idx_list, gate_list, counts, t128, nt, nullptr, nullptr);
    cvt_f32_bf16<<<2048, 256, 0, stream>>>((const float4*)w2, (ushort4*)wb, WN4);
    moe_g<FF, 2, 17, 4, false><<<8 * MAXT, 256, 0, stream>>>(
        h, wb, nullptr, out, idx_list, gate_list, counts, t128, nt, nullptr, nullptr);
  }
}

// Round 11
// 511.774 us; speedup vs baseline: 1.3256x; 1.2625x over previous
//
#include <hip/hip_runtime.h>
#include <hip/hip_bf16.h>
#include <stdint.h>

// ---------------- problem constants ----------------
#define N_TOK 8192
#define DIM   1024
#define FF    4096
#define NEXP  8
#define MAXT  136    // 128-row tiles: sum ceil(ce/128) <= 135; 136 = 8 XCDs * 17
#define WN4   (NEXP * FF * DIM / 4)   // float4 count of one weight tensor (8388608)
#define NGRP  2048   // 4-token groups

// ---------------- workspace layout (bytes) ----------------
#define OFF_COUNTS 0ull
#define OFF_NT     64ull
#define OFF_T128   8192ull            // 136*16
#define OFF_IDX    16384ull           // 8*8192*4
#define OFF_GATE   278528ull          // 262144
#define OFF_BH     540672ull          // 2048*8*4 = 65536
#define OFF_SEL    606208ull          // 8192*16 = 131072 (ends 737280 < 1048576)
#define OFF_XB     1048576ull         // 8192*1024*2
#define OFF_H      17825792ull        // 17408*4096*2 fits in 150,994,944
#define OFF_WB     168820736ull       // 8*4096*1024*2 (w1b; w2b aliased if small ws)
#define OFF_W2B    235929600ull       // separate w2b when workspace permits
#define NEED       235929600ull
#define NEED2      303038464ull       // OFF_W2B + 67,108,864

typedef __attribute__((ext_vector_type(8))) short s16x8;   // 8 bf16 MFMA frag
typedef __attribute__((ext_vector_type(4))) float f32x4;   // MFMA accum

__device__ __forceinline__ unsigned short f2bf(float f) {
  union { float f; unsigned int u; } v; v.f = f;
  unsigned int u = v.u;
  unsigned int r = (u + 0x7FFFu + ((u >> 16) & 1u)) >> 16;  // RNE
  return (unsigned short)r;
}
__device__ __forceinline__ ushort4 bf4(float4 f) {
  ushort4 u;
  u.x = f2bf(f.x); u.y = f2bf(f.y); u.z = f2bf(f.z); u.w = f2bf(f.w);
  return u;
}

// gelu: 0.5*x*(1+erf(x/sqrt2)), erf via A&S 7.1.26 (|err|<1.5e-7)
__device__ __forceinline__ float gelu_f(float x) {
  float s = x * 0.70710678118654752f;
  float a = fabsf(s);
  float t = 1.0f / fmaf(0.3275911f, a, 1.0f);
  float p = t * fmaf(t, fmaf(t, fmaf(t, fmaf(t, 1.061405429f, -1.453152027f),
                                     1.421413741f), -0.284496736f), 0.254829592f);
  float e = __expf(-a * a);
  float erf_a = 1.0f - p * e;
  float erf_s = (s >= 0.0f) ? erf_a : -erf_a;
  return 0.5f * x * (1.0f + erf_s);
}

// async global -> LDS, 16B per lane (dest = wave-uniform base + lane*16)
__device__ __forceinline__ void load_lds16(const void* g, void* l) {
  __builtin_amdgcn_global_load_lds(
      (const __attribute__((address_space(1))) unsigned int*)g,
      (__attribute__((address_space(3))) unsigned int*)l, 16, 0, 0);
}

// ---------------- f32 -> bf16 bulk convert (serial fallback) ----------------
__global__ __launch_bounds__(256) void cvt_f32_bf16(const float4* __restrict__ in,
                                                    ushort4* __restrict__ out, int n4) {
  int i = blockIdx.x * 256 + threadIdx.x;
  int stride = gridDim.x * 256;
  for (; i < n4; i += stride) out[i] = bf4(in[i]);
}

// ---------------- K1: router (8/9 of blocks) + fat w1-cvt blocks (1/9) -------
// NO GLOBAL ATOMICS (r10 post-mortem: 16K device atomics on one cache line ==
// ~205 us serial chain == the 249 us router). Per-block LDS histogram -> bh;
// per-token top-2 record -> sel. K2 scans + scatters deterministically.
__global__ __launch_bounds__(256) void router_cvt(
    const float* __restrict__ x, const float* __restrict__ rw,
    int* __restrict__ bh, int4* __restrict__ sel,
    unsigned short* __restrict__ xb,
    const float4* __restrict__ w1f, ushort4* __restrict__ w1o) {
  const int bid = blockIdx.x;
  if ((bid + 1) % 9 == 0) {  // ---- 256 fat w1-cvt blocks
    const int c = (bid + 1) / 9 - 1;
    const int STR = 256 * 256;
    int i = c * 256 + (int)threadIdx.x;
    for (; i + 3 * STR < WN4; i += 4 * STR) {
      float4 f0 = w1f[i], f1 = w1f[i + STR], f2 = w1f[i + 2 * STR], f3 = w1f[i + 3 * STR];
      w1o[i] = bf4(f0); w1o[i + STR] = bf4(f1);
      w1o[i + 2 * STR] = bf4(f2); w1o[i + 3 * STR] = bf4(f3);
    }
    for (; i < WN4; i += STR) w1o[i] = bf4(w1f[i]);
    return;
  }
  const int tb = bid - (bid + 1) / 9;    // 0..2047: 4-token group id
  int wid = threadIdx.x >> 6;
  int lane = threadIdx.x & 63;
  int token = tb * 4 + wid;

  __shared__ int lh[NEXP];
  if (threadIdx.x < NEXP) lh[threadIdx.x] = 0;
  __syncthreads();

  const float4* xr = (const float4*)(x + (size_t)token * DIM);
  ushort4* xw = (ushort4*)(xb + (size_t)token * DIM);
  float p[NEXP];
#pragma unroll
  for (int e = 0; e < NEXP; ++e) p[e] = 0.f;
#pragma unroll
  for (int c = 0; c < 4; ++c) {
    float4 xv = xr[c * 64 + lane];
    xw[c * 64 + lane] = bf4(xv);
#pragma unroll
    for (int e = 0; e < NEXP; ++e) {
      float4 wv = ((const float4*)(rw + (size_t)e * DIM))[c * 64 + lane];
      p[e] += xv.x * wv.x + xv.y * wv.y + xv.z * wv.z + xv.w * wv.w;
    }
  }
#pragma unroll
  for (int e = 0; e < NEXP; ++e) {
    float v = p[e];
#pragma unroll
    for (int off = 32; off > 0; off >>= 1) v += __shfl_xor(v, off, 64);
    p[e] = v;
  }
  if (lane == 0) {
    int e0 = 0; float v0 = p[0];
#pragma unroll
    for (int e = 1; e < NEXP; ++e) if (p[e] > v0) { v0 = p[e]; e0 = e; }
    int e1 = (e0 == 0) ? 1 : 0; float v1 = -3.4e38f;
#pragma unroll
    for (int e = 0; e < NEXP; ++e) if (e != e0 && p[e] > v1) { v1 = p[e]; e1 = e; }
    float ex = __expf(v1 - v0);
    float g0 = 1.0f / (1.0f + ex);
    float g1 = ex / (1.0f + ex);
    atomicAdd(&lh[e0], 1);               // LDS atomics: block-local, cheap
    atomicAdd(&lh[e1], 1);
    sel[token] = make_int4(e0, e1, __float_as_int(g0), __float_as_int(g1));
  }
  __syncthreads();
  if (threadIdx.x < NEXP) bh[tb * NEXP + threadIdx.x] = lh[threadIdx.x];
}

// ---------------- K2: scan + schedule + scatter (ONE block, 1024 thr) --------
// Waves 0..7: per-expert exclusive prefix over the 2048 group histograms
// (shfl-scan, 32 chunks of 64) -> s_bb in LDS; counts[e] to global.
// Thread 0: builds the 128-row tile table (identical to old schedule_kernel).
// All 16 waves: scatter the 16384 (token,gate) entries; group-local ranks via
// static pairwise compares (no runtime-indexed arrays).
__global__ __launch_bounds__(1024) void scan_scatter(
    const int* __restrict__ bh, const int4* __restrict__ sel,
    int* __restrict__ counts, int4* __restrict__ t128, int* __restrict__ nt,
    int* __restrict__ idx_list, float* __restrict__ gate_list) {
  extern __shared__ int s_bb[];        // [NGRP][NEXP] = 64 KiB
  __shared__ int s_cnt[NEXP];
  const int tid = threadIdx.x;
  const int wave = tid >> 6, lane = tid & 63;

  if (wave < NEXP) {
    const int e = wave;
    int running = 0;
    for (int c = 0; c < NGRP / 64; ++c) {
      const int b = c * 64 + lane;
      int v = bh[b * NEXP + e];
      int incl = v;
#pragma unroll
      for (int off = 1; off < 64; off <<= 1) {
        int y = __shfl_up(incl, off, 64);
        if (lane >= off) incl += y;
      }
      s_bb[b * NEXP + e] = running + (incl - v);   // exclusive prefix
      running += __shfl(incl, 63, 64);
    }
    if (lane == 0) { s_cnt[e] = running; counts[e] = running; }
  }
  __syncthreads();

  if (tid == 0) {  // tile table (matches old schedule_kernel exactly)
    int a = 0, g = 0;
#pragma unroll
    for (int e = 0; e < NEXP; ++e) {
      int c = s_cnt[e];
      int n2 = (c + 127) >> 7;
      for (int i = 0; i < n2; ++i) t128[a++] = make_int4(e, i << 7, g + (i << 7), 0);
      g += n2 << 7;
    }
    nt[0] = a;
  }

  for (int g = tid; g < NGRP; g += 1024) {
    int4 s0 = sel[g * 4 + 0], s1 = sel[g * 4 + 1];
    int4 s2 = sel[g * 4 + 2], s3 = sel[g * 4 + 3];
#define EMIT(i, sv, r0, r1)                                              \
    {                                                                     \
      int p0 = s_bb[g * NEXP + sv.x] + (r0);                              \
      int p1 = s_bb[g * NEXP + sv.y] + (r1);                              \
      idx_list[sv.x * N_TOK + p0] = g * 4 + i;                            \
      gate_list[sv.x * N_TOK + p0] = __int_as_float(sv.z);                \
      idx_list[sv.y * N_TOK + p1] = g * 4 + i;                            \
      gate_list[sv.y * N_TOK + p1] = __int_as_float(sv.w);                \
    }
    EMIT(0, s0, 0, 0);
    EMIT(1, s1, (s0.x == s1.x) + (s0.y == s1.x), (s0.x == s1.y) + (s0.y == s1.y));
    EMIT(2, s2, (s0.x == s2.x) + (s0.y == s2.x) + (s1.x == s2.x) + (s1.y == s2.x),
                (s0.x == s2.y) + (s0.y == s2.y) + (s1.x == s2.y) + (s1.y == s2.y));
    EMIT(3, s3, (s0.x == s3.x) + (s0.y == s3.x) + (s1.x == s3.x) + (s1.y == s3.x) +
                (s2.x == s3.x) + (s2.y == s3.x),
                (s0.x == s3.y) + (s0.y == s3.y) + (s1.x == s3.y) + (s1.y == s3.y) +
                (s2.x == s3.y) + (s2.y == s3.y));
#undef EMIT
  }
}

// ---------------- grouped GEMM: 128x128, BK=64, 4 waves, single buffer -------
// Proven r8 skeleton: {stage; sync; ds_read+MFMA; sync} per K-tile; latency
// hidden by co-resident blocks (m114). L2-aware chunked XCD mapping (r8).
// LDS conflict-free via source-pre-swizzled 16B-slot XOR (r3: 0 conflicts).
// FUSE (GEMM1, sep-ws only): per-XCD 578 slots = 544 GEMM + 34 fat cvt slots
// (every 17th) -> ~6% of resident blocks are cvt; w2 f32->bf16 drafts on
// GEMM1's idle HBM bandwidth without stealing co-residency (r9 lesson).
// EPI==1: H[gbase+r] = gelu(A_gathered @ W^T) (bf16).
// EPI==2: atomicAdd(Out[token], gate * (H @ W^T)).
template <int KDIM, int EPI, int TPX, int CW, bool FUSE>
__global__ __launch_bounds__(256, 4) void moe_g(
    const unsigned short* __restrict__ Abase, const unsigned short* __restrict__ Bb,
    unsigned short* __restrict__ Hout, float* __restrict__ Out,
    const int* __restrict__ idx_list, const float* __restrict__ gate_list,
    const int* __restrict__ counts, const int4* __restrict__ table,
    const int* __restrict__ n_tiles,
    const float4* __restrict__ cvt_src, ushort4* __restrict__ cvt_dst) {
  int xcd, r0;
  if constexpr (FUSE) {
    const int bid = blockIdx.x;           // grid = 8 * 578
    xcd = bid & 7;
    const int r = bid >> 3;               // 0..577 per XCD
    if ((r + 1) % 17 == 0) {              // ---- 34 cvt slots per XCD (272 total)
      const int c = xcd * 34 + (r + 1) / 17 - 1;
      const int STR = 272 * 256;
      int i = c * 256 + (int)threadIdx.x;
      for (; i + 3 * STR < WN4; i += 4 * STR) {
        float4 f0 = cvt_src[i], f1 = cvt_src[i + STR];
        float4 f2 = cvt_src[i + 2 * STR], f3 = cvt_src[i + 3 * STR];
        cvt_dst[i] = bf4(f0); cvt_dst[i + STR] = bf4(f1);
        cvt_dst[i + 2 * STR] = bf4(f2); cvt_dst[i + 3 * STR] = bf4(f3);
      }
      for (; i < WN4; i += STR) cvt_dst[i] = bf4(cvt_src[i]);
      return;
    }
    r0 = r - (r + 1) / 17;                // 0..543: identical walk to non-fused
  } else {
    xcd = blockIdx.x & 7;
    r0 = blockIdx.x >> 3;
  }
  const int chunk = r0 / (TPX * CW), q = r0 % (TPX * CW);
  const int ty = xcd * TPX + q / CW;
  const int cx = chunk * CW + q % CW;
  if (ty >= *n_tiles) return;
  int4 te = table[ty];
  const int e = te.x, row_start = te.y, gbase = te.z;
  const int ce = counts[e];
  const int tid = threadIdx.x;
  const int wid = tid >> 6, lane = tid & 63;
  const int colT = cx * 128;

  __shared__ unsigned short Al[128 * 64];
  __shared__ unsigned short Bl[128 * 64];

  // staging: thread -> rows {i*32+sr}, phys 16B-slot tid&7; source pre-swizzled
  const int sr = tid >> 3;
  const int scol = ((tid & 7) ^ (sr & 7)) * 8;
  size_t aoff[4], boff[4];
#pragma unroll
  for (int i = 0; i < 4; ++i) {
    int r = i * 32 + sr;
    if constexpr (EPI == 1) {
      int rl = row_start + r; if (rl >= ce) rl = ce - 1;   // clamp padded rows
      int tok = idx_list[e * N_TOK + rl];
      aoff[i] = ((size_t)tok * KDIM + scol) * 2;
    } else {
      aoff[i] = ((size_t)(gbase + r) * KDIM + scol) * 2;
    }
    boff[i] = ((size_t)e * FF * DIM + (size_t)(colT + r) * KDIM + scol) * 2;
  }
  const char* Ag = (const char*)Abase;
  const char* Bg = (const char*)Bb;
  const int NT = KDIM / 64;

  const int wr = (wid >> 1) * 64, wc = (wid & 1) * 64;   // wave 64x64 sub-tile
  const int r16 = lane & 15, kg = lane >> 4;
  const int x7 = r16 & 7;

  f32x4 acc[4][4] = {};

  for (int t = 0; t < NT; ++t) {
    {
      char* da = (char*)Al + tid * 16;
      char* db = (char*)Bl + tid * 16;
      size_t ko = (size_t)t * 128;   // 64 elems * 2B
#pragma unroll
      for (int i = 0; i < 4; ++i) load_lds16(Ag + aoff[i] + ko, da + i * 4096);
#pragma unroll
      for (int i = 0; i < 4; ++i) load_lds16(Bg + boff[i] + ko, db + i * 4096);
    }
    __syncthreads();
    const char* Ap = (const char*)Al + (wr + r16) * 128;
    const char* Bp = (const char*)Bl + (wc + r16) * 128;
#pragma unroll
    for (int kf = 0; kf < 2; ++kf) {
      const int so = ((kf * 4 + kg) ^ x7) * 16;   // swizzled 16B-slot
      s16x8 a[4], b[4];
#pragma unroll
      for (int m = 0; m < 4; ++m) a[m] = *(const s16x8*)(Ap + m * 2048 + so);
#pragma unroll
      for (int n = 0; n < 4; ++n) b[n] = *(const s16x8*)(Bp + n * 2048 + so);
#pragma unroll
      for (int m = 0; m < 4; ++m)
#pragma unroll
        for (int n = 0; n < 4; ++n)
          acc[m][n] = __builtin_amdgcn_mfma_f32_16x16x32_bf16(a[m], b[n], acc[m][n], 0, 0, 0);
    }
    __syncthreads();
  }

  if constexpr (EPI == 1) {
#pragma unroll
    for (int m = 0; m < 4; ++m) {
      const int row_l = wr + m * 16 + kg * 4;
#pragma unroll
      for (int j = 0; j < 4; ++j) {
        size_t hrow = (size_t)(gbase + row_l + j) * FF + colT + wc;
#pragma unroll
        for (int n = 0; n < 4; ++n)
          Hout[hrow + n * 16 + r16] = f2bf(gelu_f(acc[m][n][j]));
      }
    }
  } else {
#pragma unroll
    for (int m = 0; m < 4; ++m) {
      const int row_l = wr + m * 16 + kg * 4;
#pragma unroll
      for (int j = 0; j < 4; ++j) {
        int r = row_start + row_l + j;
        if (r < ce) {
          int tok = idx_list[e * N_TOK + r];
          float g = gate_list[e * N_TOK + r];
          float* orow = Out + (size_t)tok * DIM + colT + wc;
#pragma unroll
          for (int n = 0; n < 4; ++n)
            atomicAdd(&orow[n * 16 + r16], acc[m][n][j] * g);
        }
      }
    }
  }
}

// ---------------- launch ----------------
extern "C" void kernel_launch(void* const* d_in, const int* in_sizes, int n_in,
                              void* d_out, int out_size, void* d_ws, size_t ws_size,
                              hipStream_t stream) {
  const float* x  = (const float*)d_in[0];
  const float* rw = (const float*)d_in[1];
  const float* w1 = (const float*)d_in[2];
  const float* w2 = (const float*)d_in[3];
  float* out = (float*)d_out;
  char* ws = (char*)d_ws;
  if (ws_size < NEED) return;
  const bool sep = ws_size >= NEED2;   // ws_size is fixed -> deterministic

  int*   counts    = (int*)(ws + OFF_COUNTS);
  int*   nt        = (int*)(ws + OFF_NT);
  int4*  t128      = (int4*)(ws + OFF_T128);
  int*   idx_list  = (int*)(ws + OFF_IDX);
  float* gate_list = (float*)(ws + OFF_GATE);
  int*   bh        = (int*)(ws + OFF_BH);
  int4*  sel       = (int4*)(ws + OFF_SEL);
  unsigned short* xb  = (unsigned short*)(ws + OFF_XB);
  unsigned short* h   = (unsigned short*)(ws + OFF_H);
  unsigned short* wb  = (unsigned short*)(ws + OFF_WB);
  unsigned short* w2b = (unsigned short*)(ws + OFF_W2B);

  hipFuncSetAttribute(reinterpret_cast<const void*>(&scan_scatter),
                      hipFuncAttributeMaxDynamicSharedMemorySize, 65536);

  hipMemsetAsync(d_out, 0, (size_t)N_TOK * DIM * sizeof(float), stream);

  // K1: router (2048 blocks) + fat w1->bf16 blocks (256), 8:1 interleave
  router_cvt<<<2304, 256, 0, stream>>>(x, rw, bh, sel, xb,
                                       (const float4*)w1, (ushort4*)wb);
  // K2: scan + table + scatter (deterministic, no global atomics anywhere)
  scan_scatter<<<1, 1024, 65536, stream>>>(bh, sel, counts, t128, nt,
                                           idx_list, gate_list);

  if (sep) {
    // GEMM1 (544 GEMM + 34 cvt slots per XCD) * 8 = 4624 blocks
    moe_g<DIM, 1, 17, 8, true><<<8 * 578, 256, 0, stream>>>(
        xb, wb, h, nullptr, idx_list, gate_list, counts, t128, nt,
        (const float4*)w2, (ushort4*)w2b);
    moe_g<FF, 2, 17, 4, false><<<8 * MAXT, 256, 0, stream>>>(
        h, w2b, nullptr, out, idx_list, gate_list, counts, t128, nt, nullptr, nullptr);
  } else {
    moe_g<DIM, 1, 17, 8, false><<<32 * MAXT, 256, 0, stream>>>(
        xb, wb, h, nullptr, idx_list, gate_list, counts, t128, nt, nullptr, nullptr);
    cvt_f32_bf16<<<2048, 256, 0, stream>>>((const float4*)w2, (ushort4*)wb, WN4);
    moe_g<FF, 2, 17, 4, false><<<8 * MAXT, 256, 0, stream>>>(
        h, wb, nullptr, out, idx_list, gate_list, counts, t128, nt, nullptr, nullptr);
  }
}